// Round 3
// baseline (8397.018 us; speedup 1.0000x reference)
//
#include <hip/hip_runtime.h>
#include <math.h>

// Problem constants
static constexpr int B_   = 32;
static constexpr int L_   = 1024;
static constexpr int CIN_ = 21;
static constexpr int D_   = 512;
static constexpr int H_   = 8;
static constexpr int E_   = 64;
static constexpr int DFF_ = 2048;
static constexpr int M_   = 64;   // MODES

// ---------------------------------------------------------------------------
// Trig tables: tcos/tsin [64][1024] for forward DFT; tcat [1024][128] for the
// inverse DFT expressed as an NT GEMM:
//   out[l] = sum_k acat[.,k]*tcat[l][k],  k<64: Re coeff (2cos, m=0 -> 1),
//   k>=64: Im coeff (-2sin, m=0 -> 0); 1/1024 baked in.
// ---------------------------------------------------------------------------
__global__ void k_tables(float* tcos, float* tsin, float* tcat) {
    int idx = blockIdx.x * 256 + threadIdx.x;   // 0 .. 131071
    if (idx < 65536) {
        int l = idx & 1023, m = idx >> 10;
        int r = (m * l) & 1023;
        double th = (double)r * (6.283185307179586 / 1024.0);
        tcos[idx] = (float)cos(th);
        tsin[idx] = (float)sin(th);
    }
    if (idx < 131072) {
        int k = idx & 127, l = idx >> 7;
        int m = k & 63;
        int r = (m * l) & 1023;
        double th = (double)r * (6.283185307179586 / 1024.0);
        float v;
        if (k < 64) v = (m == 0) ? 1.0f : (float)(2.0 * cos(th));
        else        v = (m == 0) ? 0.0f : (float)(-2.0 * sin(th));
        tcat[idx] = v * (1.0f / 1024.0f);
    }
}

// ---------------------------------------------------------------------------
// Embedding: circular conv1d(k=3, no bias) + sinusoidal PE
// ---------------------------------------------------------------------------
__global__ void k_embed(const float* __restrict__ xe, const float* __restrict__ cw,
                        float* __restrict__ x) {
    int idx = blockIdx.x * 256 + threadIdx.x;   // B*L*D
    int d = idx & 511;
    int l = (idx >> 9) & 1023;
    int b = idx >> 19;
    float acc = 0.f;
    #pragma unroll
    for (int k = 0; k < 3; ++k) {
        int ls = l + k - 1;
        ls = (ls + L_) & (L_ - 1);          // L pow2 -> wrap
        const float* xr = xe + ((size_t)b * L_ + ls) * CIN_;
        const float* wr = cw + (size_t)d * (CIN_ * 3) + k;
        #pragma unroll
        for (int c = 0; c < CIN_; ++c) acc += xr[c] * wr[c * 3];
    }
    int i2 = d >> 1;
    float div = expf(-(float)(2 * i2) * 0.017988946039015984f); // ln(1e4)/512
    float arg = (float)l * div;
    float pe = (d & 1) ? cosf(arg) : sinf(arg);
    x[idx] = acc + pe;
}

// ---------------------------------------------------------------------------
// Generic NT GEMM: C[m,n] = act( sum_k A[m,k]*W[n,k] + bias[n] ) + add[m,n]
// A: [M,K] lda=K, W: [N,*] row stride ldw, C/add: [M,N]
// 64x64 tile, 256 threads, 4x4 per thread
// ---------------------------------------------------------------------------
template<bool BIAS, bool GELU, bool ADD>
__global__ void k_gemm_nt(const float* __restrict__ A, const float* __restrict__ W,
                          const float* __restrict__ bias, const float* __restrict__ addp,
                          float* __restrict__ C, int M, int N, int K, int ldw) {
    __shared__ float As[16][64];
    __shared__ float Ws[16][64];
    int n0 = blockIdx.x * 64;
    int m0 = blockIdx.y * 64;
    int tid = threadIdx.x;
    int tx = tid & 15, ty = tid >> 4;
    int lr = tid >> 2;           // 0..63
    int lc = (tid & 3) * 4;      // 0,4,8,12
    const float* Ap = A + (size_t)(m0 + lr) * K + lc;
    const float* Wp = W + (size_t)(n0 + lr) * ldw + lc;
    float acc[4][4] = {};
    for (int k0 = 0; k0 < K; k0 += 16) {
        float4 av = *(const float4*)(Ap + k0);
        float4 wv = *(const float4*)(Wp + k0);
        As[lc + 0][lr] = av.x; As[lc + 1][lr] = av.y;
        As[lc + 2][lr] = av.z; As[lc + 3][lr] = av.w;
        Ws[lc + 0][lr] = wv.x; Ws[lc + 1][lr] = wv.y;
        Ws[lc + 2][lr] = wv.z; Ws[lc + 3][lr] = wv.w;
        __syncthreads();
        #pragma unroll
        for (int k = 0; k < 16; ++k) {
            float4 a4 = *(const float4*)&As[k][ty * 4];
            float4 w4 = *(const float4*)&Ws[k][tx * 4];
            float av_[4] = {a4.x, a4.y, a4.z, a4.w};
            float wv_[4] = {w4.x, w4.y, w4.z, w4.w};
            #pragma unroll
            for (int i = 0; i < 4; ++i)
                #pragma unroll
                for (int j = 0; j < 4; ++j)
                    acc[i][j] += av_[i] * wv_[j];
        }
        __syncthreads();
    }
    #pragma unroll
    for (int i = 0; i < 4; ++i) {
        int m = m0 + ty * 4 + i;
        #pragma unroll
        for (int j = 0; j < 4; ++j) {
            int n = n0 + tx * 4 + j;
            float v = acc[i][j];
            if (BIAS) v += bias[n];
            if (GELU) v = 0.5f * v * (1.f + erff(v * 0.70710678118f));
            if (ADD)  v += addp[(size_t)m * N + n];
            C[(size_t)m * N + n] = v;
        }
    }
}

// ---------------------------------------------------------------------------
// Forward truncated DFT: ft_re/ft_im [B][64m][512c] from q [B][L][D]
// ---------------------------------------------------------------------------
__global__ void k_dft(const float* __restrict__ q, const float* __restrict__ tc,
                      const float* __restrict__ ts, float* __restrict__ fre,
                      float* __restrict__ fim) {
    int b = blockIdx.x;
    int c = blockIdx.y * 64 + (threadIdx.x & 63);
    int m = blockIdx.z * 4 + (threadIdx.x >> 6);
    const float* qp = q + (size_t)b * L_ * D_ + c;
    const float* tcp = tc + m * L_;
    const float* tsp = ts + m * L_;
    float ar = 0.f, ai = 0.f;
    for (int l = 0; l < L_; ++l) {
        float v = qp[(size_t)l * D_];
        ar += v * tcp[l];
        ai -= v * tsp[l];
    }
    size_t o = ((size_t)b * M_ + m) * D_ + c;
    fre[o] = ar;
    fim[o] = ai;
}

// ---------------------------------------------------------------------------
// Complex per-mode channel mix -> acat [B*H*64o][128] (Re | Im)
// ---------------------------------------------------------------------------
__global__ void k_modemix(const float* __restrict__ fre, const float* __restrict__ fim,
                          const float* __restrict__ wre, const float* __restrict__ wim,
                          float* __restrict__ acat) {
    __shared__ float wr_s[64][64];   // [e][o]
    __shared__ float wi_s[64][64];
    __shared__ float fr_s[32][64];   // [b][e]
    __shared__ float fi_s[32][64];
    int h = blockIdx.x >> 6, m = blockIdx.x & 63;
    int tid = threadIdx.x;
    for (int i = tid; i < 4096; i += 256) {
        int e = i >> 6, o = i & 63;
        size_t widx = (((size_t)(h * 64 + e)) * 64 + o) * 64 + m;
        wr_s[e][o] = wre[widx];
        wi_s[e][o] = wim[widx];
    }
    for (int i = tid; i < 2048; i += 256) {
        int b = i >> 6, e = i & 63;
        size_t fidx = ((size_t)b * 64 + m) * 512 + h * 64 + e;
        fr_s[b][e] = fre[fidx];
        fi_s[b][e] = fim[fidx];
    }
    __syncthreads();
    int o = tid & 63, bg = tid >> 6;
    for (int bb = bg; bb < 32; bb += 4) {
        float accr = 0.f, acci = 0.f;
        #pragma unroll 8
        for (int e = 0; e < 64; ++e) {
            float wr = wr_s[e][o], wi = wi_s[e][o];
            float fr = fr_s[bb][e], fi = fi_s[bb][e];
            accr += fr * wr - fi * wi;
            acci += fr * wi + fi * wr;
        }
        size_t base = (((size_t)(bb * 8 + h)) * 64 + o) * 128;
        acat[base + m]      = accr;
        acat[base + 64 + m] = acci;
    }
}

// ---------------------------------------------------------------------------
// moving-average decomp residual: out = in - mean25(in) with edge clamp
// ---------------------------------------------------------------------------
__global__ void k_madiff(const float* __restrict__ in, float* __restrict__ out) {
    int idx = blockIdx.x * 256 + threadIdx.x;   // B*L*D
    int d = idx & 511;
    int l = (idx >> 9) & 1023;
    int b = idx >> 19;
    const float* base = in + (size_t)b * L_ * D_ + d;
    float s = 0.f;
    #pragma unroll
    for (int k = -12; k <= 12; ++k) {
        int ll = l + k;
        ll = ll < 0 ? 0 : (ll > 1023 ? 1023 : ll);
        s += base[(size_t)ll * 512];
    }
    out[idx] = in[idx] - s * (1.f / 25.f);
}

// ---------------------------------------------------------------------------
// LayerNorm over last dim (512), one 256-thread block per row
// ---------------------------------------------------------------------------
__global__ void k_layernorm(const float* __restrict__ in, const float* __restrict__ g,
                            const float* __restrict__ bta, float* __restrict__ out) {
    int row = blockIdx.x;
    int tid = threadIdx.x;
    const float* r = in + (size_t)row * 512;
    float v0 = r[tid], v1 = r[tid + 256];
    float s = v0 + v1, s2 = v0 * v0 + v1 * v1;
    #pragma unroll
    for (int off = 32; off; off >>= 1) {
        s  += __shfl_down(s, off);
        s2 += __shfl_down(s2, off);
    }
    __shared__ float ws[4], ws2[4];
    if ((tid & 63) == 0) { ws[tid >> 6] = s; ws2[tid >> 6] = s2; }
    __syncthreads();
    if (tid == 0) {
        float ts = ws[0] + ws[1] + ws[2] + ws[3];
        float t2 = ws2[0] + ws2[1] + ws2[2] + ws2[3];
        ws[0] = ts; ws2[0] = t2;
    }
    __syncthreads();
    float mu = ws[0] * (1.f / 512.f);
    float var = ws2[0] * (1.f / 512.f) - mu * mu;
    float rs = rsqrtf(var + 1e-5f);
    float* o = out + (size_t)row * 512;
    o[tid]       = (v0 - mu) * rs * g[tid]       + bta[tid];
    o[tid + 256] = (v1 - mu) * rs * g[tid + 256] + bta[tid + 256];
}

// per-(b,d) mean over L
__global__ void k_colmean(const float* __restrict__ in, float* __restrict__ mean) {
    int b = blockIdx.x;
    int d = blockIdx.y * 256 + threadIdx.x;
    const float* p = in + (size_t)b * L_ * 512 + d;
    float s = 0.f;
    for (int l = 0; l < L_; ++l) s += p[(size_t)l * 512];
    mean[b * 512 + d] = s * (1.f / 1024.f);
}

__global__ void k_subcol(float* __restrict__ x, const float* __restrict__ mean) {
    int idx = blockIdx.x * 256 + threadIdx.x;
    int d = idx & 511;
    int b = idx >> 19;
    x[idx] -= mean[b * 512 + d];
}

// final regression: out[b] = dot(x[b,:], reg_w) + reg_b
__global__ void k_reg(const float* __restrict__ x, const float* __restrict__ rw,
                      const float* __restrict__ rb, float* __restrict__ out) {
    int b = blockIdx.x;
    const float* p = x + (size_t)b * L_ * 512;
    float s = 0.f;
    for (int i = threadIdx.x; i < L_ * 512; i += 256) s += p[i] * rw[i];
    #pragma unroll
    for (int off = 32; off; off >>= 1) s += __shfl_down(s, off);
    __shared__ float ws[4];
    if ((threadIdx.x & 63) == 0) ws[threadIdx.x >> 6] = s;
    __syncthreads();
    if (threadIdx.x == 0) out[b] = ws[0] + ws[1] + ws[2] + ws[3] + rb[0];
}

// ---------------------------------------------------------------------------
extern "C" void kernel_launch(void* const* d_in, const int* in_sizes, int n_in,
                              void* d_out, int out_size, void* d_ws, size_t ws_size,
                              hipStream_t stream) {
    const float* x_enc  = (const float*)d_in[0];
    const float* conv_w = (const float*)d_in[1];
    const float* wq     = (const float*)d_in[2];
    const float* bq     = (const float*)d_in[3];
    const float* wo     = (const float*)d_in[4];
    const float* bo     = (const float*)d_in[5];
    const float* fw_re  = (const float*)d_in[6];
    const float* fw_im  = (const float*)d_in[7];
    const float* c1w    = (const float*)d_in[8];
    const float* c2w    = (const float*)d_in[9];
    const float* enc_g  = (const float*)d_in[10];
    const float* enc_b  = (const float*)d_in[11];
    const float* ff_w   = (const float*)d_in[12];
    const float* ff_b   = (const float*)d_in[13];
    const float* ffn_g  = (const float*)d_in[14];
    const float* ffn_b  = (const float*)d_in[15];
    const float* reg_w  = (const float*)d_in[16];
    const float* reg_b  = (const float*)d_in[17];
    float* out = (float*)d_out;

    // Workspace layout (total ~46.4M floats = ~186 MB)
    const size_t NBL = (size_t)B_ * L_ * D_;            // 16,777,216
    float* ws   = (float*)d_ws;
    float* bufA = ws;                                   // [B,L,D]          64 MiB
    float* bufB = bufA + NBL;                           // q / new_x / xy   64 MiB
    float* bufY = bufB + NBL;                           // [32768,256] ffn  32 MiB
    float* ftre = bufY + (size_t)32768 * 256;           // [B,64,512]        4 MiB
    float* ftim = ftre + (size_t)B_ * M_ * D_;          // [B,64,512]        4 MiB
    float* acat = ftim + (size_t)B_ * M_ * D_;          // [B*H*64,128]      8 MiB
    float* tcos = acat + (size_t)B_ * H_ * 64 * 128;    // [64,1024]
    float* tsin = tcos + 65536;
    float* tcat = tsin + 65536;                         // [1024,128]
    float* cmean = tcat + 131072;                       // [B,512]
    const size_t need_bytes = ((size_t)(cmean + B_ * 512 - ws)) * sizeof(float);
    if (ws_size < need_bytes) return;   // leaves d_out poisoned -> clean absmax fail (diagnostic)

    const int BLD = B_ * L_ * D_;
    dim3 blk(256);

    k_tables<<<131072 / 256, blk, 0, stream>>>(tcos, tsin, tcat);
    k_embed<<<BLD / 256, blk, 0, stream>>>(x_enc, conv_w, bufA);

    float* cur = bufA;
    float* alt = bufB;
    const dim3 gemm_grid(8, 512);       // N=512, M=32768

    for (int l = 0; l < 2; ++l) {
        const float* wq_l = wq + (size_t)l * 512 * 512;
        const float* bq_l = bq + l * 512;
        const float* wo_l = wo + (size_t)l * 512 * 512;
        const float* bo_l = bo + l * 512;
        const float* fwre_l = fw_re + (size_t)l * H_ * E_ * E_ * M_;
        const float* fwim_l = fw_im + (size_t)l * H_ * E_ * E_ * M_;
        const float* c1w_l = c1w + (size_t)l * DFF_ * D_;
        const float* c2w_l = c2w + (size_t)l * D_ * DFF_;

        // q = x @ wq^T + bq  -> alt
        k_gemm_nt<true, false, false><<<gemm_grid, blk, 0, stream>>>(
            cur, wq_l, bq_l, nullptr, alt, 32768, 512, 512, 512);
        // truncated rfft of q
        k_dft<<<dim3(B_, 8, 16), blk, 0, stream>>>(alt, tcos, tsin, ftre, ftim);
        // complex mode mixing -> acat  (q now dead)
        k_modemix<<<512, blk, 0, stream>>>(ftre, ftim, fwre_l, fwim_l, acat);
        // irfft as GEMM -> alt = new_x [B,H,E,L] (overwrites q)
        k_gemm_nt<false, false, false><<<dim3(16, 256), blk, 0, stream>>>(
            acat, tcat, nullptr, nullptr, alt, 16384, 1024, 128, 128);
        // x = x + (view(new_x) @ wo^T + bo)   (in-place on cur, tile-local add)
        k_gemm_nt<true, false, true><<<gemm_grid, blk, 0, stream>>>(
            alt, wo_l, bo_l, cur, cur, 32768, 512, 512, 512);
        // x = x - moving_avg(x) -> alt ; swap
        k_madiff<<<BLD / 256, blk, 0, stream>>>(cur, alt);
        { float* t = cur; cur = alt; alt = t; }
        // FFN, chunked by 256 DFF columns; xy accumulates in alt (old x, dead)
        for (int c = 0; c < 8; ++c) {
            const float* w1c = c1w_l + (size_t)c * 256 * 512;   // rows [c*256,...)
            const float* w2c = c2w_l + (size_t)c * 256;         // col chunk, ldw=2048
            k_gemm_nt<false, true, false><<<dim3(4, 512), blk, 0, stream>>>(
                cur, w1c, nullptr, nullptr, bufY, 32768, 256, 512, 512);
            if (c == 0)
                k_gemm_nt<false, false, true><<<gemm_grid, blk, 0, stream>>>(
                    bufY, w2c, nullptr, cur, alt, 32768, 512, 256, 2048);
            else
                k_gemm_nt<false, false, true><<<gemm_grid, blk, 0, stream>>>(
                    bufY, w2c, nullptr, alt, alt, 32768, 512, 256, 2048);
        }
        // x = xy - moving_avg(xy) -> cur
        k_madiff<<<BLD / 256, blk, 0, stream>>>(alt, cur);
    }

    // my_Layernorm: LN then subtract per-(b,d) mean over L
    k_layernorm<<<32768, blk, 0, stream>>>(cur, enc_g, enc_b, alt);
    k_colmean<<<dim3(B_, 2), blk, 0, stream>>>(alt, cmean);
    k_subcol<<<BLD / 256, blk, 0, stream>>>(alt, cmean);
    // head: Linear + LayerNorm (in-place LN is row-local safe)
    k_gemm_nt<true, false, false><<<gemm_grid, blk, 0, stream>>>(
        alt, ff_w, ff_b, nullptr, cur, 32768, 512, 512, 512);
    k_layernorm<<<32768, blk, 0, stream>>>(cur, ffn_g, ffn_b, cur);
    // regression
    k_reg<<<B_, blk, 0, stream>>>(cur, reg_w, reg_b, out);
}

// Round 4
// 2255.794 us; speedup vs baseline: 3.7224x; 3.7224x over previous
//
#include <hip/hip_runtime.h>
#include <math.h>

static constexpr int B_   = 32;
static constexpr int L_   = 1024;
static constexpr int CIN_ = 21;
static constexpr int D_   = 512;
static constexpr int H_   = 8;
static constexpr int E_   = 64;
static constexpr int DFF_ = 2048;
static constexpr int M_   = 64;   // MODES

typedef unsigned short u16;
typedef __attribute__((ext_vector_type(8))) short bf16x8;
typedef __attribute__((ext_vector_type(4))) float f32x4;
typedef __attribute__((ext_vector_type(4))) unsigned short u16x4;

// RNE float->bf16 (bit-level, no header dependency)
static __device__ __forceinline__ u16 f2b(float f) {
    unsigned u = __float_as_uint(f);
    unsigned r = (u + 0x7fffu + ((u >> 16) & 1u)) >> 16;
    return (u16)r;
}

// ---------------------------------------------------------------------------
// Tables: TRIG16 [128 mcat][1024 l] bf16 (rows 0-63 cos, 64-127 -sin) for the
// forward DFT-as-GEMM; TCAT16 [1024 l][128 kcat] bf16 for the inverse DFT
// (k<64: re coeff, m=0->1 else 2cos; k>=64: im coeff, m=0->0 else -2sin;
// 1/1024 baked in); PE fp32 [1024][512] sinusoidal positional encoding.
// ---------------------------------------------------------------------------
__global__ void k_tables(u16* trig, u16* tcat, float* pe) {
    int idx = blockIdx.x * 256 + threadIdx.x;   // 0 .. 524287
    if (idx < 131072) {                          // trig [mc][l]
        int l = idx & 1023, mc = idx >> 10;
        int m = mc & 63;
        double th = (double)((m * l) & 1023) * (6.283185307179586 / 1024.0);
        float v = (mc < 64) ? (float)cos(th) : (float)(-sin(th));
        trig[idx] = f2b(v);
    }
    if (idx < 131072) {                          // tcat [l][k]
        int k = idx & 127, l = idx >> 7;
        int m = k & 63;
        double th = (double)((m * l) & 1023) * (6.283185307179586 / 1024.0);
        float v;
        if (k < 64) v = (m == 0) ? 1.0f : (float)(2.0 * cos(th));
        else        v = (m == 0) ? 0.0f : (float)(-2.0 * sin(th));
        tcat[idx] = f2b(v * (1.0f / 1024.0f));
    }
    if (idx < 524288) {                          // pe [l][d]
        int d = idx & 511, l = idx >> 9;
        int i2 = d >> 1;
        float div = expf(-(float)(2 * i2) * 0.017988946039015984f);
        float arg = (float)l * div;
        pe[idx] = (d & 1) ? cosf(arg) : sinf(arg);
    }
}

// generic fp32 -> bf16 cast (n multiple of 4)
__global__ void k_cast(const float* __restrict__ in, u16* __restrict__ out, int n4) {
    int i = blockIdx.x * 256 + threadIdx.x;
    if (i < n4) {
        float4 v = ((const float4*)in)[i];
        u16x4 o = { f2b(v.x), f2b(v.y), f2b(v.z), f2b(v.w) };
        ((u16x4*)out)[i] = o;
    }
}

// ---------------------------------------------------------------------------
// Embedding: circular conv1d(k=3) + PE table. Block = 512 threads (one per d),
// 32 l-values per thread; x_enc strip staged in LDS; weights in registers.
// ---------------------------------------------------------------------------
__global__ __launch_bounds__(512) void k_embed(
        const float* __restrict__ xe, const float* __restrict__ cw,
        const float* __restrict__ pe, float* __restrict__ x32,
        u16* __restrict__ x16) {
    __shared__ float strip[34][21];
    int b = blockIdx.y, l0 = blockIdx.x * 32;
    int d = threadIdx.x;
    for (int i = d; i < 34 * 21; i += 512) {
        int r = i / 21, c = i - r * 21;
        int ls = (l0 + r - 1 + 1024) & 1023;
        strip[r][c] = xe[((size_t)b * 1024 + ls) * 21 + c];
    }
    __syncthreads();
    float w[3][21];
    #pragma unroll
    for (int k = 0; k < 3; ++k)
        #pragma unroll
        for (int c = 0; c < 21; ++c)
            w[k][c] = cw[(size_t)d * 63 + c * 3 + k];
    for (int li = 0; li < 32; ++li) {
        float acc = 0.f;
        #pragma unroll
        for (int k = 0; k < 3; ++k)
            #pragma unroll
            for (int c = 0; c < 21; ++c)
                acc += strip[li + k][c] * w[k][c];
        int l = l0 + li;
        float v = acc + pe[(size_t)l * 512 + d];
        size_t o = ((size_t)b * 1024 + l) * 512 + d;
        x32[o] = v;
        x16[o] = f2b(v);
    }
}

// ---------------------------------------------------------------------------
// bf16 MFMA NT GEMM: C[m,n] = ep( sum_k A[m,k]*W[n,k] ), 128x128 tile,
// 256 threads = 4 waves (2x2 of 64x64), 16x16x32 MFMA, BK=32, reg-staged LDS.
// Optional z-batching via strideA/strideC (W shared across batch).
// ---------------------------------------------------------------------------
template<bool BIAS, bool GELU, bool ADD, bool WF32, bool WBF16>
__global__ __launch_bounds__(256, 2) void k_mfma(
        const u16* __restrict__ A, const u16* __restrict__ W,
        const float* __restrict__ bias, const float* addp,
        float* C32, u16* C16,
        int K, int lda, int ldw, int ldc, long strideA, long strideC) {
    __shared__ __align__(16) u16 As[128 * 32];
    __shared__ __align__(16) u16 Bs[128 * 32];
    const int tid  = threadIdx.x;
    const int lane = tid & 63, wid = tid >> 6;
    const int m0 = blockIdx.y * 128, n0 = blockIdx.x * 128;
    A += (size_t)blockIdx.z * strideA;
    const size_t cbase = (size_t)blockIdx.z * strideC;

    // staging: wave wid covers rows [wid*32, wid*32+32); lane -> (row, col8)
    const int srow = lane >> 2, scol = (lane & 3) * 8;
    const u16* ga0 = A + (size_t)(m0 + wid * 32 + srow) * lda + scol;
    const u16* ga1 = A + (size_t)(m0 + wid * 32 + 16 + srow) * lda + scol;
    const u16* gb0 = W + (size_t)(n0 + wid * 32 + srow) * ldw + scol;
    const u16* gb1 = W + (size_t)(n0 + wid * 32 + 16 + srow) * ldw + scol;
    u16* la0 = &As[(wid * 32 + srow) * 32 + scol];
    u16* la1 = &As[(wid * 32 + 16 + srow) * 32 + scol];
    u16* lb0 = &Bs[(wid * 32 + srow) * 32 + scol];
    u16* lb1 = &Bs[(wid * 32 + 16 + srow) * 32 + scol];

    const int wr = wid >> 1, wc = wid & 1;
    const int fr = lane & 15, fg = lane >> 4;

    f32x4 acc[4][4];
    #pragma unroll
    for (int i = 0; i < 4; ++i)
        #pragma unroll
        for (int j = 0; j < 4; ++j)
            acc[i][j] = f32x4{0.f, 0.f, 0.f, 0.f};

    bf16x8 ra0 = *(const bf16x8*)ga0;
    bf16x8 ra1 = *(const bf16x8*)ga1;
    bf16x8 rb0 = *(const bf16x8*)gb0;
    bf16x8 rb1 = *(const bf16x8*)gb1;

    for (int k0 = 0; k0 < K; k0 += 32) {
        __syncthreads();                    // previous iter's ds_reads done
        *(bf16x8*)la0 = ra0;  *(bf16x8*)la1 = ra1;
        *(bf16x8*)lb0 = rb0;  *(bf16x8*)lb1 = rb1;
        __syncthreads();                    // tile ready
        if (k0 + 32 < K) {                  // prefetch next K-tile (hidden under MFMA)
            ra0 = *(const bf16x8*)(ga0 + k0 + 32);
            ra1 = *(const bf16x8*)(ga1 + k0 + 32);
            rb0 = *(const bf16x8*)(gb0 + k0 + 32);
            rb1 = *(const bf16x8*)(gb1 + k0 + 32);
        }
        bf16x8 af[4], bfr[4];
        #pragma unroll
        for (int i = 0; i < 4; ++i) {
            af[i]  = *(const bf16x8*)&As[(wr * 64 + i * 16 + fr) * 32 + fg * 8];
            bfr[i] = *(const bf16x8*)&Bs[(wc * 64 + i * 16 + fr) * 32 + fg * 8];
        }
        #pragma unroll
        for (int i = 0; i < 4; ++i)
            #pragma unroll
            for (int j = 0; j < 4; ++j)
                acc[i][j] = __builtin_amdgcn_mfma_f32_16x16x32_bf16(
                    af[i], bfr[j], acc[i][j], 0, 0, 0);
    }

    #pragma unroll
    for (int i = 0; i < 4; ++i) {
        #pragma unroll
        for (int j = 0; j < 4; ++j) {
            #pragma unroll
            for (int r = 0; r < 4; ++r) {
                int row = m0 + wr * 64 + i * 16 + fg * 4 + r;
                int col = n0 + wc * 64 + j * 16 + fr;
                float v = acc[i][j][r];
                if (BIAS) v += bias[col];
                if (GELU) v = 0.5f * v * (1.f + erff(v * 0.70710678118f));
                size_t o = cbase + (size_t)row * ldc + col;
                if (ADD)  v += addp[o];
                if (WF32) C32[o] = v;
                if (WBF16) C16[o] = f2b(v);
            }
        }
    }
}

// ---------------------------------------------------------------------------
// Transpose + cast: q fp32 [B*L][512] -> QT bf16 [B][512][1024]
// ---------------------------------------------------------------------------
__global__ void k_tcast(const float* __restrict__ in, u16* __restrict__ out) {
    __shared__ float t[64][65];
    int b = blockIdx.z, l0 = blockIdx.y * 64, c0 = blockIdx.x * 64;
    int j = threadIdx.x & 63, i0 = threadIdx.x >> 6;
    for (int i = i0; i < 64; i += 4)
        t[i][j] = in[((size_t)b * 1024 + l0 + i) * 512 + c0 + j];
    __syncthreads();
    for (int i = i0; i < 64; i += 4)
        out[((size_t)b * 512 + c0 + i) * 1024 + l0 + j] = f2b(t[j][i]);
}

// ---------------------------------------------------------------------------
// Complex per-mode channel mix from ftT fp32 [B][512][128] -> acat bf16
// [B*H*64o][128] (Re | Im).  grid 512 = (h,m), block 256.
// ---------------------------------------------------------------------------
__global__ void k_modemix(const float* __restrict__ ftT,
                          const float* __restrict__ wre, const float* __restrict__ wim,
                          u16* __restrict__ acat) {
    __shared__ float wr_s[64][64];   // [e][o]
    __shared__ float wi_s[64][64];
    __shared__ float fr_s[32][64];   // [b][e]
    __shared__ float fi_s[32][64];
    int h = blockIdx.x >> 6, m = blockIdx.x & 63;
    int tid = threadIdx.x;
    for (int i = tid; i < 4096; i += 256) {
        int e = i >> 6, o = i & 63;
        size_t widx = (((size_t)(h * 64 + e)) * 64 + o) * 64 + m;
        wr_s[e][o] = wre[widx];
        wi_s[e][o] = wim[widx];
    }
    for (int i = tid; i < 2048; i += 256) {
        int b = i >> 6, e = i & 63;
        size_t fidx = ((size_t)(b * 512) + h * 64 + e) * 128 + m;
        fr_s[b][e] = ftT[fidx];
        fi_s[b][e] = ftT[fidx + 64];
    }
    __syncthreads();
    int o = tid & 63, bg = tid >> 6;
    for (int bb = bg; bb < 32; bb += 4) {
        float accr = 0.f, acci = 0.f;
        #pragma unroll 8
        for (int e = 0; e < 64; ++e) {
            float wr = wr_s[e][o], wi = wi_s[e][o];
            float fr = fr_s[bb][e], fi = fi_s[bb][e];
            accr += fr * wr - fi * wi;
            acci += fr * wi + fi * wr;
        }
        size_t base = (((size_t)(bb * 8 + h)) * 64 + o) * 128;
        acat[base + m]      = f2b(accr);
        acat[base + 64 + m] = f2b(acci);
    }
}

// ---------------------------------------------------------------------------
// moving-average decomp residual: out = in - mean25(in), fp32 + bf16 mirror
// ---------------------------------------------------------------------------
__global__ void k_madiff(const float* __restrict__ in, float* __restrict__ out,
                         u16* __restrict__ out16) {
    int idx = blockIdx.x * 256 + threadIdx.x;
    int d = idx & 511;
    int l = (idx >> 9) & 1023;
    int b = idx >> 19;
    const float* base = in + (size_t)b * L_ * D_ + d;
    float s = 0.f;
    #pragma unroll
    for (int k = -12; k <= 12; ++k) {
        int ll = l + k;
        ll = ll < 0 ? 0 : (ll > 1023 ? 1023 : ll);
        s += base[(size_t)ll * 512];
    }
    float v = in[idx] - s * (1.f / 25.f);
    out[idx] = v;
    out16[idx] = f2b(v);
}

// ---------------------------------------------------------------------------
// LayerNorm over last dim (512)
// ---------------------------------------------------------------------------
__global__ void k_layernorm(const float* __restrict__ in, const float* __restrict__ g,
                            const float* __restrict__ bta, float* __restrict__ out) {
    int row = blockIdx.x;
    int tid = threadIdx.x;
    const float* r = in + (size_t)row * 512;
    float v0 = r[tid], v1 = r[tid + 256];
    float s = v0 + v1, s2 = v0 * v0 + v1 * v1;
    #pragma unroll
    for (int off = 32; off; off >>= 1) {
        s  += __shfl_down(s, off);
        s2 += __shfl_down(s2, off);
    }
    __shared__ float ws[4], ws2[4];
    if ((tid & 63) == 0) { ws[tid >> 6] = s; ws2[tid >> 6] = s2; }
    __syncthreads();
    if (tid == 0) {
        ws[0]  = ws[0] + ws[1] + ws[2] + ws[3];
        ws2[0] = ws2[0] + ws2[1] + ws2[2] + ws2[3];
    }
    __syncthreads();
    float mu = ws[0] * (1.f / 512.f);
    float var = ws2[0] * (1.f / 512.f) - mu * mu;
    float rs = rsqrtf(var + 1e-5f);
    float* o = out + (size_t)row * 512;
    o[tid]       = (v0 - mu) * rs * g[tid]       + bta[tid];
    o[tid + 256] = (v1 - mu) * rs * g[tid + 256] + bta[tid + 256];
}

__global__ void k_colmean(const float* __restrict__ in, float* __restrict__ mean) {
    int b = blockIdx.x;
    int d = blockIdx.y * 256 + threadIdx.x;
    const float* p = in + (size_t)b * L_ * 512 + d;
    float s = 0.f;
    for (int l = 0; l < L_; ++l) s += p[(size_t)l * 512];
    mean[b * 512 + d] = s * (1.f / 1024.f);
}

// subtract per-(b,d) mean, write fp32 in place + bf16 mirror
__global__ void k_subcol(float* __restrict__ x, const float* __restrict__ mean,
                         u16* __restrict__ x16) {
    int idx = blockIdx.x * 256 + threadIdx.x;
    int d = idx & 511;
    int b = idx >> 19;
    float v = x[idx] - mean[b * 512 + d];
    x[idx] = v;
    x16[idx] = f2b(v);
}

__global__ void k_reg(const float* __restrict__ x, const float* __restrict__ rw,
                      const float* __restrict__ rb, float* __restrict__ out) {
    int b = blockIdx.x;
    const float* p = x + (size_t)b * L_ * 512;
    float s = 0.f;
    for (int i = threadIdx.x; i < L_ * 512; i += 256) s += p[i] * rw[i];
    #pragma unroll
    for (int off = 32; off; off >>= 1) s += __shfl_down(s, off);
    __shared__ float ws[4];
    if ((threadIdx.x & 63) == 0) ws[threadIdx.x >> 6] = s;
    __syncthreads();
    if (threadIdx.x == 0) out[b] = ws[0] + ws[1] + ws[2] + ws[3] + rb[0];
}

// ---------------------------------------------------------------------------
extern "C" void kernel_launch(void* const* d_in, const int* in_sizes, int n_in,
                              void* d_out, int out_size, void* d_ws, size_t ws_size,
                              hipStream_t stream) {
    const float* x_enc  = (const float*)d_in[0];
    const float* conv_w = (const float*)d_in[1];
    const float* wq     = (const float*)d_in[2];
    const float* bq     = (const float*)d_in[3];
    const float* wo     = (const float*)d_in[4];
    const float* bo     = (const float*)d_in[5];
    const float* fw_re  = (const float*)d_in[6];
    const float* fw_im  = (const float*)d_in[7];
    const float* c1w    = (const float*)d_in[8];
    const float* c2w    = (const float*)d_in[9];
    const float* enc_g  = (const float*)d_in[10];
    const float* enc_b  = (const float*)d_in[11];
    const float* ff_w   = (const float*)d_in[12];
    const float* ff_b   = (const float*)d_in[13];
    const float* ffn_g  = (const float*)d_in[14];
    const float* ffn_b  = (const float*)d_in[15];
    const float* reg_w  = (const float*)d_in[16];
    const float* reg_b  = (const float*)d_in[17];
    float* out = (float*)d_out;

    // ---- workspace layout (byte offsets; total 227,606,528 B ≈ 227.6 MB) ----
    char* wsb = (char*)d_ws;
    float* F0    = (float*)(wsb);                        // 64 MiB fp32 [B,L,D]
    float* F1    = (float*)(wsb + 67108864);             // 64 MiB fp32 [B,L,D]
    u16*   A16   = (u16*)  (wsb + 134217728);            // 32 MiB bf16 [B,L,D] (x mirror)
    u16*   U16   = (u16*)  (wsb + 167772160);            // 32 MiB bf16 (qT / new_x / y)
    u16*   AC16  = (u16*)  (wsb + 201326592);            // 4 MiB  bf16 [16384][128]
    float* FTT   = (float*)(wsb + 205520896);            // 8 MiB  fp32 [32][512][128]
    float* PE    = (float*)(wsb + 213909504);            // 2 MiB  fp32 [1024][512]
    u16*   TRIG  = (u16*)  (wsb + 216006656);            // 256 KiB [128][1024]
    u16*   TCAT  = (u16*)  (wsb + 216268800);            // 256 KiB [1024][128]
    u16*   WQ16  = (u16*)  (wsb + 216530944);            // 1 MiB [2][512][512]
    u16*   WO16  = (u16*)  (wsb + 217579520);            // 1 MiB
    u16*   C1W16 = (u16*)  (wsb + 218628096);            // 4 MiB [2][2048][512]
    u16*   C2W16 = (u16*)  (wsb + 222822400);            // 4 MiB [2][512][2048]
    u16*   FFW16 = (u16*)  (wsb + 227016704);            // 512 KiB
    float* CMEAN = (float*)(wsb + 227540992);            // 64 KiB
    const size_t need_bytes = 227606528;
    if (ws_size < need_bytes) return;   // clean diagnostic failure

    const int BLD = B_ * L_ * D_;
    dim3 blk(256);

    // tables + weight casts + embedding
    k_tables<<<2048, blk, 0, stream>>>(TRIG, TCAT, PE);
    k_cast<<<512,  blk, 0, stream>>>(wq,   WQ16,  524288 / 4);
    k_cast<<<512,  blk, 0, stream>>>(wo,   WO16,  524288 / 4);
    k_cast<<<2048, blk, 0, stream>>>(c1w,  C1W16, 2097152 / 4);
    k_cast<<<2048, blk, 0, stream>>>(c2w,  C2W16, 2097152 / 4);
    k_cast<<<256,  blk, 0, stream>>>(ff_w, FFW16, 262144 / 4);
    k_embed<<<dim3(32, 32), 512, 0, stream>>>(x_enc, conv_w, PE, F0, A16);

    float* cur = F0;
    float* alt = F1;
    const dim3 g_big(4, 256);     // M=32768, N=512

    for (int l = 0; l < 2; ++l) {
        const float* bq_l = bq + l * 512;
        const float* bo_l = bo + l * 512;
        const u16* wq16_l = WQ16 + (size_t)l * 262144;
        const u16* wo16_l = WO16 + (size_t)l * 262144;
        const u16* c1_l   = C1W16 + (size_t)l * DFF_ * D_;
        const u16* c2_l   = C2W16 + (size_t)l * D_ * DFF_;
        const float* fwre_l = fw_re + (size_t)l * H_ * E_ * E_ * M_;
        const float* fwim_l = fw_im + (size_t)l * H_ * E_ * E_ * M_;

        // q = x @ wq^T + bq -> alt (fp32)
        k_mfma<true, false, false, true, false><<<g_big, blk, 0, stream>>>(
            A16, wq16_l, bq_l, nullptr, alt, nullptr, 512, 512, 512, 512, 0, 0);
        // transpose+cast q -> U16 [b][c][l]
        k_tcast<<<dim3(8, 16, 32), blk, 0, stream>>>(alt, U16);
        // forward DFT as batched GEMM: ftT[b][c][mcat]
        k_mfma<false, false, false, true, false><<<dim3(1, 4, 32), blk, 0, stream>>>(
            U16, TRIG, nullptr, nullptr, FTT, nullptr,
            1024, 1024, 1024, 128, 512 * 1024, 512 * 128);
        // complex mode mixing -> AC16
        k_modemix<<<512, blk, 0, stream>>>(FTT, fwre_l, fwim_l, AC16);
        // inverse DFT as GEMM -> U16 = new_x bf16 [B,H,E,L]
        k_mfma<false, false, false, false, true><<<dim3(8, 128), blk, 0, stream>>>(
            AC16, TCAT, nullptr, nullptr, nullptr, U16, 128, 128, 128, 1024, 0, 0);
        // x = x + (new_x @ wo^T + bo) -> cur (in-place add)
        k_mfma<true, false, true, true, false><<<g_big, blk, 0, stream>>>(
            U16, wo16_l, bo_l, cur, cur, nullptr, 512, 512, 512, 512, 0, 0);
        // x = x - ma(x) -> alt fp32 + A16 bf16
        k_madiff<<<BLD / 256, blk, 0, stream>>>(cur, alt, A16);
        // FFN in 4 chunks of 512 DFF cols; xy accumulates into cur (old x dead)
        for (int c = 0; c < 4; ++c) {
            k_mfma<false, true, false, false, true><<<g_big, blk, 0, stream>>>(
                A16, c1_l + (size_t)c * 512 * 512, nullptr, nullptr, nullptr, U16,
                512, 512, 512, 512, 0, 0);
            k_mfma<false, false, true, true, false><<<g_big, blk, 0, stream>>>(
                U16, c2_l + (size_t)c * 512, nullptr, (c == 0 ? alt : cur), cur, nullptr,
                512, 512, 2048, 512, 0, 0);
        }
        // x = xy - ma(xy) -> alt + A16 ; swap
        k_madiff<<<BLD / 256, blk, 0, stream>>>(cur, alt, A16);
        { float* t = cur; cur = alt; alt = t; }
    }

    // my_Layernorm: LN then subtract per-(b,d) mean over L
    k_layernorm<<<32768, blk, 0, stream>>>(cur, enc_g, enc_b, alt);
    k_colmean<<<dim3(B_, 2), blk, 0, stream>>>(alt, CMEAN);
    k_subcol<<<BLD / 256, blk, 0, stream>>>(alt, CMEAN, A16);
    // head Linear + LayerNorm
    k_mfma<true, false, false, true, false><<<g_big, blk, 0, stream>>>(
        A16, FFW16, ff_b, nullptr, cur, nullptr, 512, 512, 512, 512, 0, 0);
    k_layernorm<<<32768, blk, 0, stream>>>(cur, ffn_g, ffn_b, cur);
    // regression
    k_reg<<<B_, blk, 0, stream>>>(cur, reg_w, reg_b, out);
}

// Round 6
// 1531.115 us; speedup vs baseline: 5.4842x; 1.4733x over previous
//
#include <hip/hip_runtime.h>
#include <math.h>

static constexpr int B_   = 32;
static constexpr int L_   = 1024;
static constexpr int CIN_ = 21;
static constexpr int D_   = 512;
static constexpr int H_   = 8;
static constexpr int E_   = 64;
static constexpr int DFF_ = 2048;
static constexpr int M_   = 64;   // MODES

typedef unsigned short u16;
typedef __attribute__((ext_vector_type(8))) short bf16x8;
typedef __attribute__((ext_vector_type(4))) float f32x4;
typedef __attribute__((ext_vector_type(4))) unsigned short u16x4;

// RNE float->bf16 (bit-level, no header dependency)
static __device__ __forceinline__ u16 f2b(float f) {
    unsigned u = __float_as_uint(f);
    unsigned r = (u + 0x7fffu + ((u >> 16) & 1u)) >> 16;
    return (u16)r;
}

// ---------------------------------------------------------------------------
// Tables: TRIG16 [128 mcat][1024 l] bf16 (rows 0-63 cos, 64-127 -sin) for the
// forward DFT-as-GEMM; TCAT16 [1024 l][128 kcat] bf16 for the inverse DFT
// (k<64: re coeff, m=0->1 else 2cos; k>=64: im coeff, m=0->0 else -2sin;
// 1/1024 baked in); PE fp32 [1024][512] sinusoidal positional encoding.
// ---------------------------------------------------------------------------
__global__ void k_tables(u16* trig, u16* tcat, float* pe) {
    int idx = blockIdx.x * 256 + threadIdx.x;   // 0 .. 524287
    if (idx < 131072) {                          // trig [mc][l]
        int l = idx & 1023, mc = idx >> 10;
        int m = mc & 63;
        double th = (double)((m * l) & 1023) * (6.283185307179586 / 1024.0);
        float v = (mc < 64) ? (float)cos(th) : (float)(-sin(th));
        trig[idx] = f2b(v);
    }
    if (idx < 131072) {                          // tcat [l][k]
        int k = idx & 127, l = idx >> 7;
        int m = k & 63;
        double th = (double)((m * l) & 1023) * (6.283185307179586 / 1024.0);
        float v;
        if (k < 64) v = (m == 0) ? 1.0f : (float)(2.0 * cos(th));
        else        v = (m == 0) ? 0.0f : (float)(-2.0 * sin(th));
        tcat[idx] = f2b(v * (1.0f / 1024.0f));
    }
    if (idx < 524288) {                          // pe [l][d]
        int d = idx & 511, l = idx >> 9;
        int i2 = d >> 1;
        float div = expf(-(float)(2 * i2) * 0.017988946039015984f);
        float arg = (float)l * div;
        pe[idx] = (d & 1) ? cosf(arg) : sinf(arg);
    }
}

// generic fp32 -> bf16 cast (n multiple of 4)
__global__ void k_cast(const float* __restrict__ in, u16* __restrict__ out, int n4) {
    int i = blockIdx.x * 256 + threadIdx.x;
    if (i < n4) {
        float4 v = ((const float4*)in)[i];
        u16x4 o = { f2b(v.x), f2b(v.y), f2b(v.z), f2b(v.w) };
        ((u16x4*)out)[i] = o;
    }
}

// ---------------------------------------------------------------------------
// Embedding: circular conv1d(k=3) + PE table. Block = 512 threads (one per d),
// 32 l-values per thread; x_enc strip staged in LDS; weights in registers.
// ---------------------------------------------------------------------------
__global__ __launch_bounds__(512) void k_embed(
        const float* __restrict__ xe, const float* __restrict__ cw,
        const float* __restrict__ pe, float* __restrict__ x32,
        u16* __restrict__ x16) {
    __shared__ float strip[34][21];
    int b = blockIdx.y, l0 = blockIdx.x * 32;
    int d = threadIdx.x;
    for (int i = d; i < 34 * 21; i += 512) {
        int r = i / 21, c = i - r * 21;
        int ls = (l0 + r - 1 + 1024) & 1023;
        strip[r][c] = xe[((size_t)b * 1024 + ls) * 21 + c];
    }
    __syncthreads();
    float w[3][21];
    #pragma unroll
    for (int k = 0; k < 3; ++k)
        #pragma unroll
        for (int c = 0; c < 21; ++c)
            w[k][c] = cw[(size_t)d * 63 + c * 3 + k];
    for (int li = 0; li < 32; ++li) {
        float acc = 0.f;
        #pragma unroll
        for (int k = 0; k < 3; ++k)
            #pragma unroll
            for (int c = 0; c < 21; ++c)
                acc += strip[li + k][c] * w[k][c];
        int l = l0 + li;
        float v = acc + pe[(size_t)l * 512 + d];
        size_t o = ((size_t)b * 1024 + l) * 512 + d;
        x32[o] = v;
        x16[o] = f2b(v);
    }
}

// ---------------------------------------------------------------------------
// bf16 MFMA NT GEMM: C[m,n] = ep( sum_k A[m,k]*W[n,k] ), 128x128 tile,
// 256 threads = 4 waves (2x2 of 64x64), 16x16x32 MFMA, BK=32, reg-staged LDS.
// Optional z-batching via strideA/strideC (W shared across batch).
// ---------------------------------------------------------------------------
template<bool BIAS, bool GELU, bool ADD, bool WF32, bool WBF16>
__global__ __launch_bounds__(256, 2) void k_mfma(
        const u16* __restrict__ A, const u16* __restrict__ W,
        const float* __restrict__ bias, const float* addp,
        float* C32, u16* C16,
        int K, int lda, int ldw, int ldc, long strideA, long strideC) {
    __shared__ __align__(16) u16 As[128 * 32];
    __shared__ __align__(16) u16 Bs[128 * 32];
    const int tid  = threadIdx.x;
    const int lane = tid & 63, wid = tid >> 6;
    const int m0 = blockIdx.y * 128, n0 = blockIdx.x * 128;
    A += (size_t)blockIdx.z * strideA;
    const size_t cbase = (size_t)blockIdx.z * strideC;

    // staging: wave wid covers rows [wid*32, wid*32+32); lane -> (row, col8)
    const int srow = lane >> 2, scol = (lane & 3) * 8;
    const u16* ga0 = A + (size_t)(m0 + wid * 32 + srow) * lda + scol;
    const u16* ga1 = A + (size_t)(m0 + wid * 32 + 16 + srow) * lda + scol;
    const u16* gb0 = W + (size_t)(n0 + wid * 32 + srow) * ldw + scol;
    const u16* gb1 = W + (size_t)(n0 + wid * 32 + 16 + srow) * ldw + scol;
    u16* la0 = &As[(wid * 32 + srow) * 32 + scol];
    u16* la1 = &As[(wid * 32 + 16 + srow) * 32 + scol];
    u16* lb0 = &Bs[(wid * 32 + srow) * 32 + scol];
    u16* lb1 = &Bs[(wid * 32 + 16 + srow) * 32 + scol];

    const int wr = wid >> 1, wc = wid & 1;
    const int fr = lane & 15, fg = lane >> 4;

    f32x4 acc[4][4];
    #pragma unroll
    for (int i = 0; i < 4; ++i)
        #pragma unroll
        for (int j = 0; j < 4; ++j)
            acc[i][j] = f32x4{0.f, 0.f, 0.f, 0.f};

    bf16x8 ra0 = *(const bf16x8*)ga0;
    bf16x8 ra1 = *(const bf16x8*)ga1;
    bf16x8 rb0 = *(const bf16x8*)gb0;
    bf16x8 rb1 = *(const bf16x8*)gb1;

    for (int k0 = 0; k0 < K; k0 += 32) {
        __syncthreads();                    // previous iter's ds_reads done
        *(bf16x8*)la0 = ra0;  *(bf16x8*)la1 = ra1;
        *(bf16x8*)lb0 = rb0;  *(bf16x8*)lb1 = rb1;
        __syncthreads();                    // tile ready
        if (k0 + 32 < K) {                  // prefetch next K-tile (hidden under MFMA)
            ra0 = *(const bf16x8*)(ga0 + k0 + 32);
            ra1 = *(const bf16x8*)(ga1 + k0 + 32);
            rb0 = *(const bf16x8*)(gb0 + k0 + 32);
            rb1 = *(const bf16x8*)(gb1 + k0 + 32);
        }
        bf16x8 af[4], bfr[4];
        #pragma unroll
        for (int i = 0; i < 4; ++i) {
            af[i]  = *(const bf16x8*)&As[(wr * 64 + i * 16 + fr) * 32 + fg * 8];
            bfr[i] = *(const bf16x8*)&Bs[(wc * 64 + i * 16 + fr) * 32 + fg * 8];
        }
        #pragma unroll
        for (int i = 0; i < 4; ++i)
            #pragma unroll
            for (int j = 0; j < 4; ++j)
                acc[i][j] = __builtin_amdgcn_mfma_f32_16x16x32_bf16(
                    af[i], bfr[j], acc[i][j], 0, 0, 0);
    }

    #pragma unroll
    for (int i = 0; i < 4; ++i) {
        #pragma unroll
        for (int j = 0; j < 4; ++j) {
            #pragma unroll
            for (int r = 0; r < 4; ++r) {
                int row = m0 + wr * 64 + i * 16 + fg * 4 + r;
                int col = n0 + wc * 64 + j * 16 + fr;
                float v = acc[i][j][r];
                if (BIAS) v += bias[col];
                if (GELU) v = 0.5f * v * (1.f + erff(v * 0.70710678118f));
                size_t o = cbase + (size_t)row * ldc + col;
                if (ADD)  v += addp[o];
                if (WF32) C32[o] = v;
                if (WBF16) C16[o] = f2b(v);
            }
        }
    }
}

// ---------------------------------------------------------------------------
// Transpose + cast: q fp32 [B*L][512] -> QT bf16 [B][512][1024]
// ---------------------------------------------------------------------------
__global__ void k_tcast(const float* __restrict__ in, u16* __restrict__ out) {
    __shared__ float t[64][65];
    int b = blockIdx.z, l0 = blockIdx.y * 64, c0 = blockIdx.x * 64;
    int j = threadIdx.x & 63, i0 = threadIdx.x >> 6;
    for (int i = i0; i < 64; i += 4)
        t[i][j] = in[((size_t)b * 1024 + l0 + i) * 512 + c0 + j];
    __syncthreads();
    for (int i = i0; i < 64; i += 4)
        out[((size_t)b * 512 + c0 + i) * 1024 + l0 + j] = f2b(t[j][i]);
}

// ---------------------------------------------------------------------------
// Complex per-mode channel mix from ftT fp32 [B][512][128] -> acat bf16
// [B*H*64o][128] (Re | Im).  grid 512 = (h,m), block 256.
// ---------------------------------------------------------------------------
__global__ void k_modemix(const float* __restrict__ ftT,
                          const float* __restrict__ wre, const float* __restrict__ wim,
                          u16* __restrict__ acat) {
    __shared__ float wr_s[64][64];   // [e][o]
    __shared__ float wi_s[64][64];
    __shared__ float fr_s[32][64];   // [b][e]
    __shared__ float fi_s[32][64];
    int h = blockIdx.x >> 6, m = blockIdx.x & 63;
    int tid = threadIdx.x;
    for (int i = tid; i < 4096; i += 256) {
        int e = i >> 6, o = i & 63;
        size_t widx = (((size_t)(h * 64 + e)) * 64 + o) * 64 + m;
        wr_s[e][o] = wre[widx];
        wi_s[e][o] = wim[widx];
    }
    for (int i = tid; i < 2048; i += 256) {
        int b = i >> 6, e = i & 63;
        size_t fidx = ((size_t)(b * 512) + h * 64 + e) * 128 + m;
        fr_s[b][e] = ftT[fidx];
        fi_s[b][e] = ftT[fidx + 64];
    }
    __syncthreads();
    int o = tid & 63, bg = tid >> 6;
    for (int bb = bg; bb < 32; bb += 4) {
        float accr = 0.f, acci = 0.f;
        #pragma unroll 8
        for (int e = 0; e < 64; ++e) {
            float wr = wr_s[e][o], wi = wi_s[e][o];
            float fr = fr_s[bb][e], fi = fi_s[bb][e];
            accr += fr * wr - fi * wi;
            acci += fr * wi + fi * wr;
        }
        size_t base = (((size_t)(bb * 8 + h)) * 64 + o) * 128;
        acat[base + m]      = f2b(accr);
        acat[base + 64 + m] = f2b(acci);
    }
}

// ---------------------------------------------------------------------------
// moving-average decomp residual: out = in - mean25(in), fp32 + bf16 mirror
// ---------------------------------------------------------------------------
__global__ void k_madiff(const float* __restrict__ in, float* __restrict__ out,
                         u16* __restrict__ out16) {
    int idx = blockIdx.x * 256 + threadIdx.x;
    int d = idx & 511;
    int l = (idx >> 9) & 1023;
    int b = idx >> 19;
    const float* base = in + (size_t)b * L_ * D_ + d;
    float s = 0.f;
    #pragma unroll
    for (int k = -12; k <= 12; ++k) {
        int ll = l + k;
        ll = ll < 0 ? 0 : (ll > 1023 ? 1023 : ll);
        s += base[(size_t)ll * 512];
    }
    float v = in[idx] - s * (1.f / 25.f);
    out[idx] = v;
    out16[idx] = f2b(v);
}

// ---------------------------------------------------------------------------
// LayerNorm over last dim (512)
// ---------------------------------------------------------------------------
__global__ void k_layernorm(const float* __restrict__ in, const float* __restrict__ g,
                            const float* __restrict__ bta, float* __restrict__ out) {
    int row = blockIdx.x;
    int tid = threadIdx.x;
    const float* r = in + (size_t)row * 512;
    float v0 = r[tid], v1 = r[tid + 256];
    float s = v0 + v1, s2 = v0 * v0 + v1 * v1;
    #pragma unroll
    for (int off = 32; off; off >>= 1) {
        s  += __shfl_down(s, off);
        s2 += __shfl_down(s2, off);
    }
    __shared__ float ws[4], ws2[4];
    if ((tid & 63) == 0) { ws[tid >> 6] = s; ws2[tid >> 6] = s2; }
    __syncthreads();
    if (tid == 0) {
        ws[0]  = ws[0] + ws[1] + ws[2] + ws[3];
        ws2[0] = ws2[0] + ws2[1] + ws2[2] + ws2[3];
    }
    __syncthreads();
    float mu = ws[0] * (1.f / 512.f);
    float var = ws2[0] * (1.f / 512.f) - mu * mu;
    float rs = rsqrtf(var + 1e-5f);
    float* o = out + (size_t)row * 512;
    o[tid]       = (v0 - mu) * rs * g[tid]       + bta[tid];
    o[tid + 256] = (v1 - mu) * rs * g[tid + 256] + bta[tid + 256];
}

// column-mean phase 1: partial[b][seg][d] = sum over 128 l's
__global__ __launch_bounds__(512) void k_colmean1(const float* __restrict__ in,
                                                  float* __restrict__ part) {
    int b = blockIdx.x, seg = blockIdx.y;   // 32 x 8
    int d = threadIdx.x;                    // 512
    const float* p = in + ((size_t)b * 1024 + seg * 128) * 512 + d;
    float s = 0.f;
    for (int l = 0; l < 128; ++l) s += p[(size_t)l * 512];
    part[((size_t)b * 8 + seg) * 512 + d] = s;
}

// column-mean phase 2: mean[b][d] = (sum over 8 segs) / 1024
__global__ void k_colmean2(const float* __restrict__ part, float* __restrict__ mean) {
    int i = blockIdx.x * 256 + threadIdx.x;   // 16384
    int b = i >> 9, d = i & 511;
    float s = 0.f;
    #pragma unroll
    for (int seg = 0; seg < 8; ++seg) s += part[((size_t)b * 8 + seg) * 512 + d];
    mean[i] = s * (1.f / 1024.f);
}

// subtract per-(b,d) mean, write fp32 in place + bf16 mirror
__global__ void k_subcol(float* __restrict__ x, const float* __restrict__ mean,
                         u16* __restrict__ x16) {
    int idx = blockIdx.x * 256 + threadIdx.x;
    int d = idx & 511;
    int b = idx >> 19;
    float v = x[idx] - mean[b * 512 + d];
    x[idx] = v;
    x16[idx] = f2b(v);
}

// regression phase 1: partial[b][s] = dot(x[b, s*8192 : (s+1)*8192], rw[...])
// grid (64 seg, 32 b) = 2048 blocks -> chip saturated, float4 loads
__global__ void k_regp(const float* __restrict__ x, const float* __restrict__ rw,
                       float* __restrict__ partial) {
    int s = blockIdx.x, b = blockIdx.y;
    const float4* p = (const float4*)(x + (size_t)b * 524288 + (size_t)s * 8192);
    const float4* w = (const float4*)(rw + (size_t)s * 8192);
    float sum = 0.f;
    #pragma unroll
    for (int i = 0; i < 8; ++i) {
        float4 a = p[threadIdx.x + i * 256];
        float4 c = w[threadIdx.x + i * 256];
        sum += a.x * c.x + a.y * c.y + a.z * c.z + a.w * c.w;
    }
    #pragma unroll
    for (int off = 32; off; off >>= 1) sum += __shfl_down(sum, off);
    __shared__ float ws_[4];
    if ((threadIdx.x & 63) == 0) ws_[threadIdx.x >> 6] = sum;
    __syncthreads();
    if (threadIdx.x == 0) partial[b * 64 + s] = ws_[0] + ws_[1] + ws_[2] + ws_[3];
}

// regression phase 2: out[b] = sum_s partial[b][s] + reg_b (deterministic)
__global__ void k_regf(const float* __restrict__ partial, const float* __restrict__ rb,
                       float* __restrict__ out) {
    int b = threadIdx.x;
    if (b < 32) {
        float s = 0.f;
        #pragma unroll 8
        for (int i = 0; i < 64; ++i) s += partial[b * 64 + i];
        out[b] = s + rb[0];
    }
}

// ---------------------------------------------------------------------------
extern "C" void kernel_launch(void* const* d_in, const int* in_sizes, int n_in,
                              void* d_out, int out_size, void* d_ws, size_t ws_size,
                              hipStream_t stream) {
    const float* x_enc  = (const float*)d_in[0];
    const float* conv_w = (const float*)d_in[1];
    const float* wq     = (const float*)d_in[2];
    const float* bq     = (const float*)d_in[3];
    const float* wo     = (const float*)d_in[4];
    const float* bo     = (const float*)d_in[5];
    const float* fw_re  = (const float*)d_in[6];
    const float* fw_im  = (const float*)d_in[7];
    const float* c1w    = (const float*)d_in[8];
    const float* c2w    = (const float*)d_in[9];
    const float* enc_g  = (const float*)d_in[10];
    const float* enc_b  = (const float*)d_in[11];
    const float* ff_w   = (const float*)d_in[12];
    const float* ff_b   = (const float*)d_in[13];
    const float* ffn_g  = (const float*)d_in[14];
    const float* ffn_b  = (const float*)d_in[15];
    const float* reg_w  = (const float*)d_in[16];
    const float* reg_b  = (const float*)d_in[17];
    float* out = (float*)d_out;

    // ---- workspace layout (byte offsets; total 227,606,528 B ≈ 227.6 MB) ----
    char* wsb = (char*)d_ws;
    float* F0    = (float*)(wsb);                        // 64 MiB fp32 [B,L,D]
    float* F1    = (float*)(wsb + 67108864);             // 64 MiB fp32 [B,L,D]
    u16*   A16   = (u16*)  (wsb + 134217728);            // 32 MiB bf16 [B,L,D] (x mirror)
    u16*   U16   = (u16*)  (wsb + 167772160);            // 32 MiB bf16 (qT / new_x / y)
    u16*   AC16  = (u16*)  (wsb + 201326592);            // 4 MiB  bf16 [16384][128]
    float* FTT   = (float*)(wsb + 205520896);            // 8 MiB  fp32 [32][512][128] / head partials
    float* PE    = (float*)(wsb + 213909504);            // 2 MiB  fp32 [1024][512]
    u16*   TRIG  = (u16*)  (wsb + 216006656);            // 256 KiB [128][1024]
    u16*   TCAT  = (u16*)  (wsb + 216268800);            // 256 KiB [1024][128]
    u16*   WQ16  = (u16*)  (wsb + 216530944);            // 1 MiB [2][512][512]
    u16*   WO16  = (u16*)  (wsb + 217579520);            // 1 MiB
    u16*   C1W16 = (u16*)  (wsb + 218628096);            // 4 MiB [2][2048][512]
    u16*   C2W16 = (u16*)  (wsb + 222822400);            // 4 MiB [2][512][2048]
    u16*   FFW16 = (u16*)  (wsb + 227016704);            // 512 KiB
    float* CMEAN = (float*)(wsb + 227540992);            // 64 KiB
    const size_t need_bytes = 227606528;
    if (ws_size < need_bytes) return;   // clean diagnostic failure

    const int BLD = B_ * L_ * D_;
    dim3 blk(256);

    // tables + weight casts + embedding
    k_tables<<<2048, blk, 0, stream>>>(TRIG, TCAT, PE);
    k_cast<<<512,  blk, 0, stream>>>(wq,   WQ16,  524288 / 4);
    k_cast<<<512,  blk, 0, stream>>>(wo,   WO16,  524288 / 4);
    k_cast<<<2048, blk, 0, stream>>>(c1w,  C1W16, 2097152 / 4);
    k_cast<<<2048, blk, 0, stream>>>(c2w,  C2W16, 2097152 / 4);
    k_cast<<<256,  blk, 0, stream>>>(ff_w, FFW16, 262144 / 4);
    k_embed<<<dim3(32, 32), 512, 0, stream>>>(x_enc, conv_w, PE, F0, A16);

    float* cur = F0;
    float* alt = F1;
    const dim3 g_big(4, 256);     // M=32768, N=512

    for (int l = 0; l < 2; ++l) {
        const float* bq_l = bq + l * 512;
        const float* bo_l = bo + l * 512;
        const u16* wq16_l = WQ16 + (size_t)l * 262144;
        const u16* wo16_l = WO16 + (size_t)l * 262144;
        const u16* c1_l   = C1W16 + (size_t)l * DFF_ * D_;
        const u16* c2_l   = C2W16 + (size_t)l * D_ * DFF_;
        const float* fwre_l = fw_re + (size_t)l * H_ * E_ * E_ * M_;
        const float* fwim_l = fw_im + (size_t)l * H_ * E_ * E_ * M_;

        // q = x @ wq^T + bq -> alt (fp32)
        k_mfma<true, false, false, true, false><<<g_big, blk, 0, stream>>>(
            A16, wq16_l, bq_l, nullptr, alt, nullptr, 512, 512, 512, 512, 0, 0);
        // transpose+cast q -> U16 [b][c][l]
        k_tcast<<<dim3(8, 16, 32), blk, 0, stream>>>(alt, U16);
        // forward DFT as batched GEMM: ftT[b][c][mcat]
        k_mfma<false, false, false, true, false><<<dim3(1, 4, 32), blk, 0, stream>>>(
            U16, TRIG, nullptr, nullptr, FTT, nullptr,
            1024, 1024, 1024, 128, 512 * 1024, 512 * 128);
        // complex mode mixing -> AC16
        k_modemix<<<512, blk, 0, stream>>>(FTT, fwre_l, fwim_l, AC16);
        // inverse DFT as GEMM -> U16 = new_x bf16 [B,H,E,L]
        k_mfma<false, false, false, false, true><<<dim3(8, 128), blk, 0, stream>>>(
            AC16, TCAT, nullptr, nullptr, nullptr, U16, 128, 128, 128, 1024, 0, 0);
        // x = x + (new_x @ wo^T + bo) -> cur (in-place add)
        k_mfma<true, false, true, true, false><<<g_big, blk, 0, stream>>>(
            U16, wo16_l, bo_l, cur, cur, nullptr, 512, 512, 512, 512, 0, 0);
        // x = x - ma(x) -> alt fp32 + A16 bf16
        k_madiff<<<BLD / 256, blk, 0, stream>>>(cur, alt, A16);
        // FFN in 4 chunks of 512 DFF cols; xy accumulates into cur (old x dead)
        for (int c = 0; c < 4; ++c) {
            k_mfma<false, true, false, false, true><<<g_big, blk, 0, stream>>>(
                A16, c1_l + (size_t)c * 512 * 512, nullptr, nullptr, nullptr, U16,
                512, 512, 512, 512, 0, 0);
            k_mfma<false, false, true, true, false><<<g_big, blk, 0, stream>>>(
                U16, c2_l + (size_t)c * 512, nullptr, (c == 0 ? alt : cur), cur, nullptr,
                512, 512, 2048, 512, 0, 0);
        }
        // x = xy - ma(xy) -> alt + A16 ; swap
        k_madiff<<<BLD / 256, blk, 0, stream>>>(cur, alt, A16);
        { float* t = cur; cur = alt; alt = t; }
    }

    // my_Layernorm: LN then subtract per-(b,d) mean over L
    k_layernorm<<<32768, blk, 0, stream>>>(cur, enc_g, enc_b, alt);
    k_colmean1<<<dim3(B_, 8), 512, 0, stream>>>(alt, FTT);
    k_colmean2<<<64, blk, 0, stream>>>(FTT, CMEAN);
    k_subcol<<<BLD / 256, blk, 0, stream>>>(alt, CMEAN, A16);
    // head Linear + LayerNorm
    k_mfma<true, false, false, true, false><<<g_big, blk, 0, stream>>>(
        A16, FFW16, ff_b, nullptr, cur, nullptr, 512, 512, 512, 512, 0, 0);
    k_layernorm<<<32768, blk, 0, stream>>>(cur, ffn_g, ffn_b, cur);
    // regression: two-phase deterministic reduction (partials in FTT scratch)
    k_regp<<<dim3(64, B_), blk, 0, stream>>>(cur, reg_w, FTT);
    k_regf<<<1, 64, 0, stream>>>(FTT, reg_b, out);
}